// Round 26
// baseline (231.596 us; speedup 1.0000x reference)
//
#include <hip/hip_runtime.h>
#include <hip/hip_bf16.h>
#include <math.h>

constexpr int B = 64, S = 1024, H = 1024;

typedef __attribute__((ext_vector_type(8))) short bf16x8;
typedef __attribute__((ext_vector_type(4))) float f32x4;

__device__ __forceinline__ unsigned pkbf2(float x, float y) {
    union { __hip_bfloat162 h; unsigned u; } r;
    r.h = __float22bfloat162_rn(float2{x, y});   // v_cvt_pk_bf16_f32 (RNE)
    return r.u;
}
__device__ __forceinline__ bf16x8 pack8(float4 a, float4 b) {
    union { unsigned u[4]; bf16x8 v; } r;
    r.u[0] = pkbf2(a.x, a.y);
    r.u[1] = pkbf2(a.z, a.w);
    r.u[2] = pkbf2(b.x, b.y);
    r.u[3] = pkbf2(b.z, b.w);
    return r.v;
}

__device__ __forceinline__ float tanh_fast(float x) {
    return 1.0f - 2.0f / (__expf(2.0f * x) + 1.0f);
}

// ---------------------------------------------------------------------------
// Kernel 1: hb[b][o] = attn_b[o] + sum_h hidden[b,h] * attn_W[o,h]   (f32)
// ---------------------------------------------------------------------------
__global__ __launch_bounds__(256) void k_hproj(const float* __restrict__ hidden,
                                               const float* __restrict__ attn_W,
                                               const float* __restrict__ attn_b,
                                               float* __restrict__ hb) {
    int wid  = blockIdx.x * 4 + (threadIdx.x >> 6);
    int lane = threadIdx.x & 63;
    int b = wid >> 10;
    int o = wid & 1023;
    const float* hrow = hidden + (size_t)b * H;
    const float* wrow = attn_W + (size_t)o * (2 * H);
    float acc = 0.f;
#pragma unroll
    for (int k = 0; k < 4; ++k) {
        int idx = lane * 4 + k * 256;
        float4 hv = *(const float4*)(hrow + idx);
        float4 wv = *(const float4*)(wrow + idx);
        acc += hv.x * wv.x + hv.y * wv.y + hv.z * wv.z + hv.w * wv.w;
    }
#pragma unroll
    for (int off = 32; off > 0; off >>= 1) acc += __shfl_down(acc, off, 64);
    if (lane == 0) hb[(size_t)b * H + o] = acc + attn_b[o];
}

// ---------------------------------------------------------------------------
// Kernel 2: We = attn_W[:, H:] -> bf16, MFMA B-fragment order (r15-validated).
// ---------------------------------------------------------------------------
__global__ __launch_bounds__(256) void k_convW(const float* __restrict__ attn_W,
                                               short* __restrict__ WeB2) {
    int gid = blockIdx.x * 256 + threadIdx.x;   // 131072 granules
    int lane = gid & 63;
    int kb   = (gid >> 6) & 31;
    int ot   = gid >> 11;
    int o  = ot * 16 + (lane & 15);
    int k0 = kb * 32 + (lane >> 4) * 8;
    const float* src = attn_W + (size_t)o * (2 * H) + H + k0;
    float4 a = *(const float4*)src;
    float4 c = *(const float4*)(src + 4);
    *(bf16x8*)(WeB2 + (size_t)gid * 8) = pack8(a, c);
}

// ---------------------------------------------------------------------------
// Kernel 3 (r26): reg-staged cross-barrier prefetch for A (r25-validated,
// 240->210us) PLUS half-K-step register pipeline for B:
//   bc[4] = current kh's B frags; bn[4] = next kh-slot's, loaded one MFMA
//   cluster ahead -> each B L2 load has 16 MFMA + ds_reads (+ A-write phase
//   across the iter boundary) to land, instead of stalling at use.
// Live regs ~143 (64 acc + 16 A-carried + 32 B + 16 af + addr) <= 170 cap
// at lb(256,3): 3 blocks/CU, 12 waves, 3 independent barrier groups.
// ---------------------------------------------------------------------------
__global__ __launch_bounds__(256, 3) void k_mfma_r(const float* __restrict__ enc,
                                                   const short* __restrict__ WeB2,
                                                   const float* __restrict__ v_W,
                                                   const float* __restrict__ hb,
                                                   float* __restrict__ pscore) {
    __shared__ short Abuf[2][64 * 64];    // 16 KB total
    __shared__ float red[64 * 4];         // 1 KB

    const int tid  = threadIdx.x;
    const int lane = tid & 63;
    const int wv   = tid >> 6;        // 0..3 (N quarter)
    const int t16  = lane & 15;
    const int q    = lane >> 4;

    const int L     = blockIdx.x;                  // 0..4095
    const int nbq   = (L >> 3) & 3;
    const int Mtile = (L & 7) | ((L >> 5) << 3);   // 0..1023 (64 rows each)
    const int b  = Mtile >> 4;
    const int s0 = (Mtile & 15) * 64;

    // A staging roles: 4 threads per row, 16 consecutive floats (2 granules)
    const int am = tid >> 2;          // row 0..63
    const int g0 = (tid & 3) * 2;     // granule 0,2,4,6
    const float* abase = enc + ((size_t)(s0 + am) * B + b) * H + g0 * 8;
    const int s7  = am & 7;
    const int ap0 = (g0 ^ s7) * 8;
    const int ap1 = ((g0 + 1) ^ s7) * 8;

    const int otb = nbq * 16 + wv * 4;
    const short* bptr = WeB2 + ((size_t)otb * 32 * 64 + lane) * 8;

    f32x4 acc[4][4];
#pragma unroll
    for (int mf = 0; mf < 4; ++mf)
#pragma unroll
        for (int nf = 0; nf < 4; ++nf) acc[mf][nf] = (f32x4){0.f, 0.f, 0.f, 0.f};

    const int swz = t16 & 7;
    const int nwv = wv * 64;

    float4 v0, v1, v2, v3;            // carried A prefetch regs (16 VGPR)
    bf16x8 bc0, bc1, bc2, bc3;        // current B frags (16 VGPR)
    bf16x8 bn0, bn1, bn2, bn3;        // next B frags (16 VGPR)

    // ---- prologue: data(0) -> slot0; issue A loads for data(1); B(0,kh=0)
    {
        float4 a0 = *(const float4*)(abase);
        float4 a1 = *(const float4*)(abase + 4);
        float4 a2 = *(const float4*)(abase + 8);
        float4 a3 = *(const float4*)(abase + 12);
        *(bf16x8*)&Abuf[0][am * 64 + ap0] = pack8(a0, a1);
        *(bf16x8*)&Abuf[0][am * 64 + ap1] = pack8(a2, a3);
        const float* asrc = abase + 64;
        v0 = *(const float4*)(asrc);
        v1 = *(const float4*)(asrc + 4);
        v2 = *(const float4*)(asrc + 8);
        v3 = *(const float4*)(asrc + 12);
        bc0 = *(const bf16x8*)(bptr + 0 * 16384);
        bc1 = *(const bf16x8*)(bptr + 1 * 16384);
        bc2 = *(const bf16x8*)(bptr + 2 * 16384);
        bc3 = *(const bf16x8*)(bptr + 3 * 16384);
    }
    __syncthreads();

    // ---- main loop: 16 K-tiles of 64
    for (int ks = 0; ks < 16; ++ks) {
        const int cur = ks & 1;
        const int nxt = cur ^ 1;

        // write data(ks+1) from carried regs (loads issued last iteration)
        if (ks + 1 < 16) {
            *(bf16x8*)&Abuf[nxt][am * 64 + ap0] = pack8(v0, v1);
            *(bf16x8*)&Abuf[nxt][am * 64 + ap1] = pack8(v2, v3);
        }
        // issue A loads for data(ks+2) -> carried regs
        if (ks + 2 < 16) {
            const float* asrc = abase + (ks + 2) * 64;
            v0 = *(const float4*)(asrc);
            v1 = *(const float4*)(asrc + 4);
            v2 = *(const float4*)(asrc + 8);
            v3 = *(const float4*)(asrc + 12);
        }

        const short* Ab = &Abuf[cur][0];

        // ===== kh = 0: prefetch B(ks,1) -> bn; MFMA with bc =====
        {
            const short* bsrc = bptr + (ks * 2 + 1) * 512;
            bn0 = *(const bf16x8*)(bsrc + 0 * 16384);
            bn1 = *(const bf16x8*)(bsrc + 1 * 16384);
            bn2 = *(const bf16x8*)(bsrc + 2 * 16384);
            bn3 = *(const bf16x8*)(bsrc + 3 * 16384);
            const int gp = (q ^ swz) * 8;                // gq = 0*4+q
            bf16x8 af[4];
#pragma unroll
            for (int mf = 0; mf < 4; ++mf)
                af[mf] = *(const bf16x8*)(Ab + (mf * 16 + t16) * 64 + gp);
#pragma unroll
            for (int mf = 0; mf < 4; ++mf) {
                acc[mf][0] = __builtin_amdgcn_mfma_f32_16x16x32_bf16(af[mf], bc0, acc[mf][0], 0, 0, 0);
                acc[mf][1] = __builtin_amdgcn_mfma_f32_16x16x32_bf16(af[mf], bc1, acc[mf][1], 0, 0, 0);
                acc[mf][2] = __builtin_amdgcn_mfma_f32_16x16x32_bf16(af[mf], bc2, acc[mf][2], 0, 0, 0);
                acc[mf][3] = __builtin_amdgcn_mfma_f32_16x16x32_bf16(af[mf], bc3, acc[mf][3], 0, 0, 0);
            }
            bc0 = bn0; bc1 = bn1; bc2 = bn2; bc3 = bn3;
        }

        // ===== kh = 1: prefetch B(ks+1,0) -> bn; MFMA with bc =====
        {
            if (ks + 1 < 16) {
                const short* bsrc = bptr + ((ks + 1) * 2) * 512;
                bn0 = *(const bf16x8*)(bsrc + 0 * 16384);
                bn1 = *(const bf16x8*)(bsrc + 1 * 16384);
                bn2 = *(const bf16x8*)(bsrc + 2 * 16384);
                bn3 = *(const bf16x8*)(bsrc + 3 * 16384);
            }
            const int gp = ((4 + q) ^ swz) * 8;          // gq = 1*4+q
            bf16x8 af[4];
#pragma unroll
            for (int mf = 0; mf < 4; ++mf)
                af[mf] = *(const bf16x8*)(Ab + (mf * 16 + t16) * 64 + gp);
#pragma unroll
            for (int mf = 0; mf < 4; ++mf) {
                acc[mf][0] = __builtin_amdgcn_mfma_f32_16x16x32_bf16(af[mf], bc0, acc[mf][0], 0, 0, 0);
                acc[mf][1] = __builtin_amdgcn_mfma_f32_16x16x32_bf16(af[mf], bc1, acc[mf][1], 0, 0, 0);
                acc[mf][2] = __builtin_amdgcn_mfma_f32_16x16x32_bf16(af[mf], bc2, acc[mf][2], 0, 0, 0);
                acc[mf][3] = __builtin_amdgcn_mfma_f32_16x16x32_bf16(af[mf], bc3, acc[mf][3], 0, 0, 0);
            }
            bc0 = bn0; bc1 = bn1; bc2 = bn2; bc3 = bn3;
        }
        __syncthreads();
    }

    // ---- epilogue: tanh + v_W dot over this wave's 64 o-cols
    float psum[4][4];
#pragma unroll
    for (int mf = 0; mf < 4; ++mf)
#pragma unroll
        for (int r = 0; r < 4; ++r) psum[mf][r] = 0.f;

#pragma unroll
    for (int nf = 0; nf < 4; ++nf) {
        const int o = nbq * 256 + nwv + nf * 16 + t16;
        const float hbv = hb[(size_t)b * H + o];
        const float vw  = v_W[o];
#pragma unroll
        for (int mf = 0; mf < 4; ++mf)
#pragma unroll
            for (int r = 0; r < 4; ++r)
                psum[mf][r] += vw * tanh_fast(acc[mf][nf][r] + hbv);
    }
#pragma unroll
    for (int mf = 0; mf < 4; ++mf)
#pragma unroll
        for (int r = 0; r < 4; ++r) {
#pragma unroll
            for (int off = 1; off < 16; off <<= 1)
                psum[mf][r] += __shfl_xor(psum[mf][r], off, 64);
        }
    if (t16 == 0) {
#pragma unroll
        for (int mf = 0; mf < 4; ++mf)
#pragma unroll
            for (int r = 0; r < 4; ++r)
                red[(mf * 16 + q * 4 + r) * 4 + wv] = psum[mf][r];
    }
    __syncthreads();
    if (tid < 64) {
        float s = red[tid * 4 + 0] + red[tid * 4 + 1] + red[tid * 4 + 2] + red[tid * 4 + 3];
        pscore[(size_t)nbq * (B * S) + (size_t)Mtile * 64 + tid] = s;
    }
}

// ---------------------------------------------------------------------------
// Kernel 4: combine 4 partials + mask + softmax over S. One block per b.
// ---------------------------------------------------------------------------
__global__ __launch_bounds__(256) void k_softmax(const float* __restrict__ pscore,
                                                 const int* __restrict__ mask,
                                                 float* __restrict__ out) {
    const int b = blockIdx.x;
    const int tid = threadIdx.x;
    __shared__ float sm[64];
    float v[4];
    float mx = -INFINITY;
#pragma unroll
    for (int k = 0; k < 4; ++k) {
        const int s = tid + k * 256;
        const size_t idx = (size_t)b * S + s;
        float sc = pscore[idx] + pscore[(size_t)(B * S) + idx]
                 + pscore[2 * (size_t)(B * S) + idx] + pscore[3 * (size_t)(B * S) + idx];
        sc = (mask[idx] == 0) ? -1e10f : sc;
        v[k] = sc;
        mx = fmaxf(mx, sc);
    }
#pragma unroll
    for (int off = 32; off > 0; off >>= 1) mx = fmaxf(mx, __shfl_down(mx, off, 64));
    if ((tid & 63) == 0) sm[tid >> 6] = mx;
    __syncthreads();
    if (tid == 0) {
        float m = sm[0];
        for (int k = 1; k < 4; ++k) m = fmaxf(m, sm[k]);
        sm[4] = m;
    }
    __syncthreads();
    mx = sm[4];
    float sum = 0.f;
#pragma unroll
    for (int k = 0; k < 4; ++k) { v[k] = __expf(v[k] - mx); sum += v[k]; }
#pragma unroll
    for (int off = 32; off > 0; off >>= 1) sum += __shfl_down(sum, off, 64);
    if ((tid & 63) == 0) sm[8 + (tid >> 6)] = sum;
    __syncthreads();
    if (tid == 0) sm[12] = sm[8] + sm[9] + sm[10] + sm[11];
    __syncthreads();
    const float inv = 1.f / sm[12];
#pragma unroll
    for (int k = 0; k < 4; ++k) out[(size_t)b * S + tid + k * 256] = v[k] * inv;
}

// ---------------------------------------------------------------------------
extern "C" void kernel_launch(void* const* d_in, const int* in_sizes, int n_in,
                              void* d_out, int out_size, void* d_ws, size_t ws_size,
                              hipStream_t stream) {
    const float* hidden = (const float*)d_in[0];   // (B,H)
    const float* enc    = (const float*)d_in[1];   // (S,B,H)
    const int*   mask   = (const int*)d_in[2];     // (B,S)
    const float* attn_W = (const float*)d_in[3];   // (H,2H)
    const float* attn_b = (const float*)d_in[4];   // (H,)
    const float* v_W    = (const float*)d_in[5];   // (H,)
    float* out = (float*)d_out;                    // (B,S)

    float* hb     = (float*)d_ws;                          // 64K f32   (256 KB)
    short* WeB2   = (short*)(hb + (size_t)B * H);          // 1M bf16   (2 MB)
    float* pscore = (float*)(WeB2 + (size_t)H * H);        // 256K f32  (1 MB)

    k_hproj<<<dim3((B * H) / 4), 256, 0, stream>>>(hidden, attn_W, attn_b, hb);
    k_convW<<<dim3(512), 256, 0, stream>>>(attn_W, WeB2);
    k_mfma_r<<<dim3(4096), 256, 0, stream>>>(enc, WeB2, v_W, hb, pscore);
    k_softmax<<<dim3(B), 256, 0, stream>>>(pscore, mask, out);
}

// Round 27
// 214.020 us; speedup vs baseline: 1.0821x; 1.0821x over previous
//
#include <hip/hip_runtime.h>
#include <hip/hip_bf16.h>
#include <math.h>

constexpr int B = 64, S = 1024, H = 1024;

typedef __attribute__((ext_vector_type(8))) short bf16x8;
typedef __attribute__((ext_vector_type(4))) float f32x4;

__device__ __forceinline__ unsigned pkbf2(float x, float y) {
    union { __hip_bfloat162 h; unsigned u; } r;
    r.h = __float22bfloat162_rn(float2{x, y});   // v_cvt_pk_bf16_f32 (RNE)
    return r.u;
}
__device__ __forceinline__ bf16x8 pack8(float4 a, float4 b) {
    union { unsigned u[4]; bf16x8 v; } r;
    r.u[0] = pkbf2(a.x, a.y);
    r.u[1] = pkbf2(a.z, a.w);
    r.u[2] = pkbf2(b.x, b.y);
    r.u[3] = pkbf2(b.z, b.w);
    return r.v;
}

__device__ __forceinline__ float tanh_fast(float x) {
    return 1.0f - 2.0f / (__expf(2.0f * x) + 1.0f);
}

// ---------------------------------------------------------------------------
// Kernel 1: hb[b][o] = attn_b[o] + sum_h hidden[b,h] * attn_W[o,h]   (f32)
// ---------------------------------------------------------------------------
__global__ __launch_bounds__(256) void k_hproj(const float* __restrict__ hidden,
                                               const float* __restrict__ attn_W,
                                               const float* __restrict__ attn_b,
                                               float* __restrict__ hb) {
    int wid  = blockIdx.x * 4 + (threadIdx.x >> 6);
    int lane = threadIdx.x & 63;
    int b = wid >> 10;
    int o = wid & 1023;
    const float* hrow = hidden + (size_t)b * H;
    const float* wrow = attn_W + (size_t)o * (2 * H);
    float acc = 0.f;
#pragma unroll
    for (int k = 0; k < 4; ++k) {
        int idx = lane * 4 + k * 256;
        float4 hv = *(const float4*)(hrow + idx);
        float4 wv = *(const float4*)(wrow + idx);
        acc += hv.x * wv.x + hv.y * wv.y + hv.z * wv.z + hv.w * wv.w;
    }
#pragma unroll
    for (int off = 32; off > 0; off >>= 1) acc += __shfl_down(acc, off, 64);
    if (lane == 0) hb[(size_t)b * H + o] = acc + attn_b[o];
}

// ---------------------------------------------------------------------------
// Kernel 2: We = attn_W[:, H:] -> bf16, MFMA B-fragment order (r15-validated).
// ---------------------------------------------------------------------------
__global__ __launch_bounds__(256) void k_convW(const float* __restrict__ attn_W,
                                               short* __restrict__ WeB2) {
    int gid = blockIdx.x * 256 + threadIdx.x;   // 131072 granules
    int lane = gid & 63;
    int kb   = (gid >> 6) & 31;
    int ot   = gid >> 11;
    int o  = ot * 16 + (lane & 15);
    int k0 = kb * 32 + (lane >> 4) * 8;
    const float* src = attn_W + (size_t)o * (2 * H) + H + k0;
    float4 a = *(const float4*)src;
    float4 c = *(const float4*)(src + 4);
    *(bf16x8*)(WeB2 + (size_t)gid * 8) = pack8(a, c);
}

// ---------------------------------------------------------------------------
// Kernel 3 (r27): r25's validated A-reg-pipeline (240->210us: carried-reg
// cross-barrier prefetch kills the m97 vmcnt drain) grafted onto r14's
// validated 128x256 geometry (512 thr, 8 waves = 2M x 4N, wave 64x64).
// Per-thread staging work IDENTICAL to r25 (2 granules/thread/ks, 16 carried
// VGPR) but output/block DOUBLES -> A-staging cost per output halves.
// Register profile = r25's (64 acc + ~64 arch = 128 bucket); lb(512,4) ->
// 2 blocks/CU = 16 waves. B at-use from L2 (r26 lesson: carrying B breaks
// the 128 bucket, -25% TLP). No setprio (m190).
// ---------------------------------------------------------------------------
__global__ __launch_bounds__(512, 4) void k_mfma_r(const float* __restrict__ enc,
                                                   const short* __restrict__ WeB2,
                                                   const float* __restrict__ v_W,
                                                   const float* __restrict__ hb,
                                                   float* __restrict__ pscore) {
    __shared__ short Abuf[2][128 * 64];   // 32 KB total
    __shared__ float red[128 * 4];        // 2 KB

    const int tid  = threadIdx.x;
    const int lane = tid & 63;
    const int wv   = tid >> 6;        // 0..7
    const int wr   = wv >> 2;         // 0..1  (M half)
    const int wc   = wv & 3;          // 0..3  (N quarter)
    const int t16  = lane & 15;
    const int q    = lane >> 4;

    const int L    = blockIdx.x;                  // 0..2047
    const int nbq  = (L >> 3) & 3;
    const int Mblk = (L & 7) | ((L >> 5) << 3);   // 0..511 (128 rows each)
    const int b    = Mblk >> 3;

    // A staging roles: 4 threads per row (128 rows), 16 consecutive floats
    const int am = tid >> 2;          // row 0..127
    const int g0 = (tid & 3) * 2;     // granule 0,2,4,6
    const float* abase;
    {
        int m = Mblk * 128 + am;
        int bb = m >> 10, ss = m & 1023;
        abase = enc + ((size_t)ss * 64 + bb) * 1024 + g0 * 8;
    }
    const int s7  = am & 7;
    const int ap0 = (g0 ^ s7) * 8;
    const int ap1 = ((g0 + 1) ^ s7) * 8;

    const short* bptr = WeB2 + (size_t)(nbq * 16 + wc * 4) * 16384 + lane * 8;

    f32x4 acc[4][4];
#pragma unroll
    for (int mf = 0; mf < 4; ++mf)
#pragma unroll
        for (int nf = 0; nf < 4; ++nf) acc[mf][nf] = (f32x4){0.f, 0.f, 0.f, 0.f};

    const int swz = t16 & 7;

    float4 v0, v1, v2, v3;            // carried A prefetch regs (16 VGPR)

    // ---- prologue: data(0) -> slot0 directly; issue loads for data(1)
    {
        float4 a0 = *(const float4*)(abase);
        float4 a1 = *(const float4*)(abase + 4);
        float4 a2 = *(const float4*)(abase + 8);
        float4 a3 = *(const float4*)(abase + 12);
        *(bf16x8*)&Abuf[0][am * 64 + ap0] = pack8(a0, a1);
        *(bf16x8*)&Abuf[0][am * 64 + ap1] = pack8(a2, a3);
        const float* asrc = abase + 64;
        v0 = *(const float4*)(asrc);
        v1 = *(const float4*)(asrc + 4);
        v2 = *(const float4*)(asrc + 8);
        v3 = *(const float4*)(asrc + 12);
    }
    __syncthreads();

    // ---- main loop: 16 K-tiles of 64
    for (int ks = 0; ks < 16; ++ks) {
        const int cur = ks & 1;
        const int nxt = cur ^ 1;

        // write data(ks+1) from carried regs (loads issued last iteration)
        if (ks + 1 < 16) {
            *(bf16x8*)&Abuf[nxt][am * 64 + ap0] = pack8(v0, v1);
            *(bf16x8*)&Abuf[nxt][am * 64 + ap1] = pack8(v2, v3);
        }
        // issue A loads for data(ks+2) -> carried regs
        if (ks + 2 < 16) {
            const float* asrc = abase + (ks + 2) * 64;
            v0 = *(const float4*)(asrc);
            v1 = *(const float4*)(asrc + 4);
            v2 = *(const float4*)(asrc + 8);
            v3 = *(const float4*)(asrc + 12);
        }

        const short* Ab = &Abuf[cur][0];
#pragma unroll
        for (int kh = 0; kh < 2; ++kh) {
            bf16x8 bfr[4];
#pragma unroll
            for (int nf = 0; nf < 4; ++nf)               // B at use, from L2
                bfr[nf] = *(const bf16x8*)(bptr + nf * 16384 + (ks * 2 + kh) * 512);
            const int gq = kh * 4 + q;
            const int gp = (gq ^ swz) * 8;
            bf16x8 af[4];
#pragma unroll
            for (int mf = 0; mf < 4; ++mf)
                af[mf] = *(const bf16x8*)(Ab + (wr * 64 + mf * 16 + t16) * 64 + gp);
#pragma unroll
            for (int mf = 0; mf < 4; ++mf)
#pragma unroll
                for (int nf = 0; nf < 4; ++nf)
                    acc[mf][nf] = __builtin_amdgcn_mfma_f32_16x16x32_bf16(
                        af[mf], bfr[nf], acc[mf][nf], 0, 0, 0);
        }
        __syncthreads();
    }

    // ---- epilogue: tanh + v_W dot over this wave's 64 o-cols
    float psum[4][4];
#pragma unroll
    for (int mf = 0; mf < 4; ++mf)
#pragma unroll
        for (int r = 0; r < 4; ++r) psum[mf][r] = 0.f;

#pragma unroll
    for (int nf = 0; nf < 4; ++nf) {
        const int o = nbq * 256 + wc * 64 + nf * 16 + t16;
        const float hbv = hb[(size_t)b * H + o];
        const float vw  = v_W[o];
#pragma unroll
        for (int mf = 0; mf < 4; ++mf)
#pragma unroll
            for (int r = 0; r < 4; ++r)
                psum[mf][r] += vw * tanh_fast(acc[mf][nf][r] + hbv);
    }
#pragma unroll
    for (int mf = 0; mf < 4; ++mf)
#pragma unroll
        for (int r = 0; r < 4; ++r) {
#pragma unroll
            for (int off = 1; off < 16; off <<= 1)
                psum[mf][r] += __shfl_xor(psum[mf][r], off, 64);
        }
    if (t16 == 0) {
#pragma unroll
        for (int mf = 0; mf < 4; ++mf)
#pragma unroll
            for (int r = 0; r < 4; ++r)
                red[(wr * 64 + mf * 16 + q * 4 + r) * 4 + wc] = psum[mf][r];
    }
    __syncthreads();
    if (tid < 128) {
        float s = red[tid * 4 + 0] + red[tid * 4 + 1] + red[tid * 4 + 2] + red[tid * 4 + 3];
        pscore[(size_t)nbq * (B * S) + (size_t)Mblk * 128 + tid] = s;
    }
}

// ---------------------------------------------------------------------------
// Kernel 4: combine 4 partials + mask + softmax over S. One block per b.
// ---------------------------------------------------------------------------
__global__ __launch_bounds__(256) void k_softmax(const float* __restrict__ pscore,
                                                 const int* __restrict__ mask,
                                                 float* __restrict__ out) {
    const int b = blockIdx.x;
    const int tid = threadIdx.x;
    __shared__ float sm[64];
    float v[4];
    float mx = -INFINITY;
#pragma unroll
    for (int k = 0; k < 4; ++k) {
        const int s = tid + k * 256;
        const size_t idx = (size_t)b * S + s;
        float sc = pscore[idx] + pscore[(size_t)(B * S) + idx]
                 + pscore[2 * (size_t)(B * S) + idx] + pscore[3 * (size_t)(B * S) + idx];
        sc = (mask[idx] == 0) ? -1e10f : sc;
        v[k] = sc;
        mx = fmaxf(mx, sc);
    }
#pragma unroll
    for (int off = 32; off > 0; off >>= 1) mx = fmaxf(mx, __shfl_down(mx, off, 64));
    if ((tid & 63) == 0) sm[tid >> 6] = mx;
    __syncthreads();
    if (tid == 0) {
        float m = sm[0];
        for (int k = 1; k < 4; ++k) m = fmaxf(m, sm[k]);
        sm[4] = m;
    }
    __syncthreads();
    mx = sm[4];
    float sum = 0.f;
#pragma unroll
    for (int k = 0; k < 4; ++k) { v[k] = __expf(v[k] - mx); sum += v[k]; }
#pragma unroll
    for (int off = 32; off > 0; off >>= 1) sum += __shfl_down(sum, off, 64);
    if ((tid & 63) == 0) sm[8 + (tid >> 6)] = sum;
    __syncthreads();
    if (tid == 0) sm[12] = sm[8] + sm[9] + sm[10] + sm[11];
    __syncthreads();
    const float inv = 1.f / sm[12];
#pragma unroll
    for (int k = 0; k < 4; ++k) out[(size_t)b * S + tid + k * 256] = v[k] * inv;
}

// ---------------------------------------------------------------------------
extern "C" void kernel_launch(void* const* d_in, const int* in_sizes, int n_in,
                              void* d_out, int out_size, void* d_ws, size_t ws_size,
                              hipStream_t stream) {
    const float* hidden = (const float*)d_in[0];   // (B,H)
    const float* enc    = (const float*)d_in[1];   // (S,B,H)
    const int*   mask   = (const int*)d_in[2];     // (B,S)
    const float* attn_W = (const float*)d_in[3];   // (H,2H)
    const float* attn_b = (const float*)d_in[4];   // (H,)
    const float* v_W    = (const float*)d_in[5];   // (H,)
    float* out = (float*)d_out;                    // (B,S)

    float* hb     = (float*)d_ws;                          // 64K f32   (256 KB)
    short* WeB2   = (short*)(hb + (size_t)B * H);          // 1M bf16   (2 MB)
    float* pscore = (float*)(WeB2 + (size_t)H * H);        // 256K f32  (1 MB)

    k_hproj<<<dim3((B * H) / 4), 256, 0, stream>>>(hidden, attn_W, attn_b, hb);
    k_convW<<<dim3(512), 256, 0, stream>>>(attn_W, WeB2);
    k_mfma_r<<<dim3(2048), 512, 0, stream>>>(enc, WeB2, v_W, hb, pscore);
    k_softmax<<<dim3(B), 256, 0, stream>>>(pscore, mask, out);
}

// Round 28
// 207.246 us; speedup vs baseline: 1.1175x; 1.0327x over previous
//
#include <hip/hip_runtime.h>
#include <hip/hip_bf16.h>
#include <math.h>

constexpr int B = 64, S = 1024, H = 1024;

typedef __attribute__((ext_vector_type(8))) short bf16x8;
typedef __attribute__((ext_vector_type(4))) float f32x4;

__device__ __forceinline__ unsigned pkbf2(float x, float y) {
    union { __hip_bfloat162 h; unsigned u; } r;
    r.h = __float22bfloat162_rn(float2{x, y});   // v_cvt_pk_bf16_f32 (RNE)
    return r.u;
}
__device__ __forceinline__ bf16x8 pack8(float4 a, float4 b) {
    union { unsigned u[4]; bf16x8 v; } r;
    r.u[0] = pkbf2(a.x, a.y);
    r.u[1] = pkbf2(a.z, a.w);
    r.u[2] = pkbf2(b.x, b.y);
    r.u[3] = pkbf2(b.z, b.w);
    return r.v;
}

__device__ __forceinline__ float tanh_fast(float x) {
    return 1.0f - 2.0f / (__expf(2.0f * x) + 1.0f);
}

// ---------------------------------------------------------------------------
// Kernel 1: hb[b][o] = attn_b[o] + sum_h hidden[b,h] * attn_W[o,h]   (f32)
// ---------------------------------------------------------------------------
__global__ __launch_bounds__(256) void k_hproj(const float* __restrict__ hidden,
                                               const float* __restrict__ attn_W,
                                               const float* __restrict__ attn_b,
                                               float* __restrict__ hb) {
    int wid  = blockIdx.x * 4 + (threadIdx.x >> 6);
    int lane = threadIdx.x & 63;
    int b = wid >> 10;
    int o = wid & 1023;
    const float* hrow = hidden + (size_t)b * H;
    const float* wrow = attn_W + (size_t)o * (2 * H);
    float acc = 0.f;
#pragma unroll
    for (int k = 0; k < 4; ++k) {
        int idx = lane * 4 + k * 256;
        float4 hv = *(const float4*)(hrow + idx);
        float4 wv = *(const float4*)(wrow + idx);
        acc += hv.x * wv.x + hv.y * wv.y + hv.z * wv.z + hv.w * wv.w;
    }
#pragma unroll
    for (int off = 32; off > 0; off >>= 1) acc += __shfl_down(acc, off, 64);
    if (lane == 0) hb[(size_t)b * H + o] = acc + attn_b[o];
}

// ---------------------------------------------------------------------------
// Kernel 2: We = attn_W[:, H:] -> bf16, MFMA B-fragment order (r15-validated).
// ---------------------------------------------------------------------------
__global__ __launch_bounds__(256) void k_convW(const float* __restrict__ attn_W,
                                               short* __restrict__ WeB2) {
    int gid = blockIdx.x * 256 + threadIdx.x;   // 131072 granules
    int lane = gid & 63;
    int kb   = (gid >> 6) & 31;
    int ot   = gid >> 11;
    int o  = ot * 16 + (lane & 15);
    int k0 = kb * 32 + (lane >> 4) * 8;
    const float* src = attn_W + (size_t)o * (2 * H) + H + k0;
    float4 a = *(const float4*)src;
    float4 c = *(const float4*)(src + 4);
    *(bf16x8*)(WeB2 + (size_t)gid * 8) = pack8(a, c);
}

// ---------------------------------------------------------------------------
// Kernel 3 (r25 FINAL, best validated: 210.8us total): reg-staged
// cross-barrier prefetch MFMA GEMM. 64x256 block, 4 waves, bf16 A-LDS dbuf,
// B at-use from L2. The prefetch is structured so the barrier's implicit
// vmcnt(0) drain (the m97 stall) never waits on in-flight loads:
//   top of ks:  cvt+ds_write data(ks+1) from regs loaded during ks-1
//               issue plain loads for data(ks+2) -> regs (carried, 16 VGPR)
//   body:       B at-use + A frags from Abuf[ks&1] + MFMA
//   barrier:    vmcnt naturally drained by the cvt consumption -> no stall.
// Measured: VGPR 64 (exactly the 128-unified bucket boundary with 64 AGPR
// acc), Occ 44%, bank conflicts 0, WRITE 1MB, absmax = f32 baseline.
// r26 (carry B: +20 VGPR) broke the bucket -> -25% TLP; r27 (128x256
// geometry) neutral -> staging amortization not binding. Session converged.
// ---------------------------------------------------------------------------
__global__ __launch_bounds__(256, 3) void k_mfma_r(const float* __restrict__ enc,
                                                   const short* __restrict__ WeB2,
                                                   const float* __restrict__ v_W,
                                                   const float* __restrict__ hb,
                                                   float* __restrict__ pscore) {
    __shared__ short Abuf[2][64 * 64];    // 16 KB total
    __shared__ float red[64 * 4];         // 1 KB

    const int tid  = threadIdx.x;
    const int lane = tid & 63;
    const int wv   = tid >> 6;        // 0..3 (N quarter)
    const int t16  = lane & 15;
    const int q    = lane >> 4;

    const int L     = blockIdx.x;                  // 0..4095
    const int nbq   = (L >> 3) & 3;
    const int Mtile = (L & 7) | ((L >> 5) << 3);   // 0..1023 (64 rows each)
    const int b  = Mtile >> 4;
    const int s0 = (Mtile & 15) * 64;

    // A staging roles: 4 threads per row, 16 consecutive floats (2 granules)
    const int am = tid >> 2;          // row 0..63
    const int g0 = (tid & 3) * 2;     // granule 0,2,4,6
    const float* abase = enc + ((size_t)(s0 + am) * B + b) * H + g0 * 8;
    const int s7  = am & 7;
    const int ap0 = (g0 ^ s7) * 8;
    const int ap1 = ((g0 + 1) ^ s7) * 8;

    const int otb = nbq * 16 + wv * 4;
    const short* bptr = WeB2 + ((size_t)otb * 32 * 64 + lane) * 8;

    f32x4 acc[4][4];
#pragma unroll
    for (int mf = 0; mf < 4; ++mf)
#pragma unroll
        for (int nf = 0; nf < 4; ++nf) acc[mf][nf] = (f32x4){0.f, 0.f, 0.f, 0.f};

    const int swz = t16 & 7;
    const int nwv = wv * 64;

    float4 v0, v1, v2, v3;            // carried prefetch regs (16 VGPR)

    // ---- prologue: data(0) -> slot0 directly; issue loads for data(1)
    {
        float4 a0 = *(const float4*)(abase);
        float4 a1 = *(const float4*)(abase + 4);
        float4 a2 = *(const float4*)(abase + 8);
        float4 a3 = *(const float4*)(abase + 12);
        *(bf16x8*)&Abuf[0][am * 64 + ap0] = pack8(a0, a1);
        *(bf16x8*)&Abuf[0][am * 64 + ap1] = pack8(a2, a3);
        const float* asrc = abase + 64;
        v0 = *(const float4*)(asrc);
        v1 = *(const float4*)(asrc + 4);
        v2 = *(const float4*)(asrc + 8);
        v3 = *(const float4*)(asrc + 12);
    }
    __syncthreads();

    // ---- main loop: 16 K-tiles of 64
    for (int ks = 0; ks < 16; ++ks) {
        const int cur = ks & 1;
        const int nxt = cur ^ 1;

        // write data(ks+1) from carried regs (loads issued last iteration)
        if (ks + 1 < 16) {
            *(bf16x8*)&Abuf[nxt][am * 64 + ap0] = pack8(v0, v1);
            *(bf16x8*)&Abuf[nxt][am * 64 + ap1] = pack8(v2, v3);
        }
        // issue loads for data(ks+2) -> carried regs
        if (ks + 2 < 16) {
            const float* asrc = abase + (ks + 2) * 64;
            v0 = *(const float4*)(asrc);
            v1 = *(const float4*)(asrc + 4);
            v2 = *(const float4*)(asrc + 8);
            v3 = *(const float4*)(asrc + 12);
        }

        const short* Ab = &Abuf[cur][0];
#pragma unroll
        for (int kh = 0; kh < 2; ++kh) {
            bf16x8 bfr[4];
#pragma unroll
            for (int nf = 0; nf < 4; ++nf)               // B at use, from L2
                bfr[nf] = *(const bf16x8*)(bptr + nf * 16384 + (ks * 2 + kh) * 512);
            const int gq = kh * 4 + q;
            const int gp = (gq ^ swz) * 8;
            bf16x8 af[4];
#pragma unroll
            for (int mf = 0; mf < 4; ++mf)
                af[mf] = *(const bf16x8*)(Ab + (mf * 16 + t16) * 64 + gp);
#pragma unroll
            for (int mf = 0; mf < 4; ++mf)
#pragma unroll
                for (int nf = 0; nf < 4; ++nf)
                    acc[mf][nf] = __builtin_amdgcn_mfma_f32_16x16x32_bf16(
                        af[mf], bfr[nf], acc[mf][nf], 0, 0, 0);
        }
        __syncthreads();
    }

    // ---- epilogue: tanh + v_W dot over this wave's 64 o-cols
    float psum[4][4];
#pragma unroll
    for (int mf = 0; mf < 4; ++mf)
#pragma unroll
        for (int r = 0; r < 4; ++r) psum[mf][r] = 0.f;

#pragma unroll
    for (int nf = 0; nf < 4; ++nf) {
        const int o = nbq * 256 + nwv + nf * 16 + t16;
        const float hbv = hb[(size_t)b * H + o];
        const float vw  = v_W[o];
#pragma unroll
        for (int mf = 0; mf < 4; ++mf)
#pragma unroll
            for (int r = 0; r < 4; ++r)
                psum[mf][r] += vw * tanh_fast(acc[mf][nf][r] + hbv);
    }
#pragma unroll
    for (int mf = 0; mf < 4; ++mf)
#pragma unroll
        for (int r = 0; r < 4; ++r) {
#pragma unroll
            for (int off = 1; off < 16; off <<= 1)
                psum[mf][r] += __shfl_xor(psum[mf][r], off, 64);
        }
    if (t16 == 0) {
#pragma unroll
        for (int mf = 0; mf < 4; ++mf)
#pragma unroll
            for (int r = 0; r < 4; ++r)
                red[(mf * 16 + q * 4 + r) * 4 + wv] = psum[mf][r];
    }
    __syncthreads();
    if (tid < 64) {
        float s = red[tid * 4 + 0] + red[tid * 4 + 1] + red[tid * 4 + 2] + red[tid * 4 + 3];
        pscore[(size_t)nbq * (B * S) + (size_t)Mtile * 64 + tid] = s;
    }
}

// ---------------------------------------------------------------------------
// Kernel 4: combine 4 partials + mask + softmax over S. One block per b.
// ---------------------------------------------------------------------------
__global__ __launch_bounds__(256) void k_softmax(const float* __restrict__ pscore,
                                                 const int* __restrict__ mask,
                                                 float* __restrict__ out) {
    const int b = blockIdx.x;
    const int tid = threadIdx.x;
    __shared__ float sm[64];
    float v[4];
    float mx = -INFINITY;
#pragma unroll
    for (int k = 0; k < 4; ++k) {
        const int s = tid + k * 256;
        const size_t idx = (size_t)b * S + s;
        float sc = pscore[idx] + pscore[(size_t)(B * S) + idx]
                 + pscore[2 * (size_t)(B * S) + idx] + pscore[3 * (size_t)(B * S) + idx];
        sc = (mask[idx] == 0) ? -1e10f : sc;
        v[k] = sc;
        mx = fmaxf(mx, sc);
    }
#pragma unroll
    for (int off = 32; off > 0; off >>= 1) mx = fmaxf(mx, __shfl_down(mx, off, 64));
    if ((tid & 63) == 0) sm[tid >> 6] = mx;
    __syncthreads();
    if (tid == 0) {
        float m = sm[0];
        for (int k = 1; k < 4; ++k) m = fmaxf(m, sm[k]);
        sm[4] = m;
    }
    __syncthreads();
    mx = sm[4];
    float sum = 0.f;
#pragma unroll
    for (int k = 0; k < 4; ++k) { v[k] = __expf(v[k] - mx); sum += v[k]; }
#pragma unroll
    for (int off = 32; off > 0; off >>= 1) sum += __shfl_down(sum, off, 64);
    if ((tid & 63) == 0) sm[8 + (tid >> 6)] = sum;
    __syncthreads();
    if (tid == 0) sm[12] = sm[8] + sm[9] + sm[10] + sm[11];
    __syncthreads();
    const float inv = 1.f / sm[12];
#pragma unroll
    for (int k = 0; k < 4; ++k) out[(size_t)b * S + tid + k * 256] = v[k] * inv;
}

// ---------------------------------------------------------------------------
extern "C" void kernel_launch(void* const* d_in, const int* in_sizes, int n_in,
                              void* d_out, int out_size, void* d_ws, size_t ws_size,
                              hipStream_t stream) {
    const float* hidden = (const float*)d_in[0];   // (B,H)
    const float* enc    = (const float*)d_in[1];   // (S,B,H)
    const int*   mask   = (const int*)d_in[2];     // (B,S)
    const float* attn_W = (const float*)d_in[3];   // (H,2H)
    const float* attn_b = (const float*)d_in[4];   // (H,)
    const float* v_W    = (const float*)d_in[5];   // (H,)
    float* out = (float*)d_out;                    // (B,S)

    float* hb     = (float*)d_ws;                          // 64K f32   (256 KB)
    short* WeB2   = (short*)(hb + (size_t)B * H);          // 1M bf16   (2 MB)
    float* pscore = (float*)(WeB2 + (size_t)H * H);        // 256K f32  (1 MB)

    k_hproj<<<dim3((B * H) / 4), 256, 0, stream>>>(hidden, attn_W, attn_b, hb);
    k_convW<<<dim3(512), 256, 0, stream>>>(attn_W, WeB2);
    k_mfma_r<<<dim3(4096), 256, 0, stream>>>(enc, WeB2, v_W, hb, pscore);
    k_softmax<<<dim3(B), 256, 0, stream>>>(pscore, mask, out);
}